// Round 1
// baseline (419.226 us; speedup 1.0000x reference)
//
#include <hip/hip_runtime.h>

#define DEV __device__ __forceinline__

typedef unsigned short u16;
typedef __attribute__((ext_vector_type(4))) float f32x4;
typedef __attribute__((ext_vector_type(8))) short short8;

// ---------- bf16 helpers (manual, RNE) ----------
DEV u16 f2bf(float f) {
  union { float f; unsigned u; } c; c.f = f;
  unsigned u = c.u;
  unsigned r = (u + 0x7FFFu + ((u >> 16) & 1u)) >> 16;
  return (u16)r;
}
DEV float bf2f(u16 h) {
  union { unsigned u; float f; } c; c.u = ((unsigned)h) << 16;
  return c.f;
}

// ---------- async global -> LDS (16B per lane) ----------
DEV void gload16(const void* g, void* l) {
  __builtin_amdgcn_global_load_lds(
      (__attribute__((address_space(1))) void*)(g),
      (__attribute__((address_space(3))) void*)(l), 16, 0, 0);
}

// ---------- cast fp32 -> bf16 (vectorized) ----------
__global__ __launch_bounds__(256) void cast_f32_bf16_kernel(
    const float* __restrict__ in, u16* __restrict__ out, int n4) {
  int i = blockIdx.x * blockDim.x + threadIdx.x;
  if (i >= n4) return;
  float4 v = reinterpret_cast<const float4*>(in)[i];
  ushort4 o;
  o.x = f2bf(v.x); o.y = f2bf(v.y); o.z = f2bf(v.z); o.w = f2bf(v.w);
  reinterpret_cast<ushort4*>(out)[i] = o;
}

// ---------- tiled transpose (+cast) : out[c][r] = bf16(in[r][c+col_off]) ----------
template <typename TIN>
__global__ __launch_bounds__(256) void transpose_to_bf16_kernel(
    const TIN* __restrict__ in, int ld_in, int col_off,
    u16* __restrict__ out, int ld_out) {
  __shared__ float tile[32][33];
  int c0 = blockIdx.x * 32, r0 = blockIdx.y * 32;
  int tx = threadIdx.x, ty = threadIdx.y;
#pragma unroll
  for (int j = 0; j < 4; ++j) {
    int r = r0 + ty + j * 8;
    TIN raw = in[(size_t)r * ld_in + col_off + c0 + tx];
    float v;
    if constexpr (sizeof(TIN) == 4) v = (float)raw;
    else v = bf2f((u16)raw);
    tile[ty + j * 8][tx] = v;
  }
  __syncthreads();
#pragma unroll
  for (int j = 0; j < 4; ++j) {
    out[(size_t)(c0 + ty + j * 8) * ld_out + r0 + tx] = f2bf(tile[tx][ty + j * 8]);
  }
}

// ---------- GEMM: C[M,N] = A[M,K] * Bt[N,K]^T (+bias)*scale, optional ReLU ----------
// 128x128 tile, BK=32, 4 waves (2x2), mfma_f32_16x16x32_bf16, double-buffered
// global_load_lds staging with XOR chunk-swizzle (s(r) = (r>>1)&3 on 16B chunks).
template <typename OutT, bool RELU>
__global__ __launch_bounds__(256) void gemm_bt_kernel(
    const u16* __restrict__ A, int lda,
    const u16* __restrict__ Bt, int ldb,
    const float* __restrict__ bias,
    OutT* __restrict__ C, int ldc,
    int K, float scale) {
  __shared__ __align__(16) u16 lds[2][2][128 * 32];
  const int lane = threadIdx.x & 63;
  const int wid = threadIdx.x >> 6;
  const int wr = wid >> 1, wc = wid & 1;
  const int lr = lane & 15, hi = lane >> 4;
  const int rb = blockIdx.y, cb = blockIdx.x;
  const int r_in = lane >> 2;  // staging: row within 16-row group
  const int c_in = lane & 3;   // staging: 16B chunk within 64B row

  const u16* Abase = A + (size_t)(rb * 128) * lda;
  const u16* Bbase = Bt + (size_t)(cb * 128) * ldb;

  f32x4 acc[4][4];
  const f32x4 zero = {0.f, 0.f, 0.f, 0.f};
#pragma unroll
  for (int m = 0; m < 4; ++m)
#pragma unroll
    for (int n = 0; n < 4; ++n) acc[m][n] = zero;

  auto stage = [&](int bf, int t) {
#pragma unroll
    for (int j = 0; j < 2; ++j) {
      int r = wid * 16 + j * 64 + r_in;
      int csrc = c_in ^ ((r >> 1) & 3);
      gload16(Abase + (size_t)r * lda + t * 32 + csrc * 8,
              &lds[bf][0][(wid * 16 + j * 64) * 32]);
      gload16(Bbase + (size_t)r * ldb + t * 32 + csrc * 8,
              &lds[bf][1][(wid * 16 + j * 64) * 32]);
    }
  };

  const int sw = (lr >> 1) & 3;
  auto compute = [&](int bf) {
    const u16* la = lds[bf][0];
    const u16* lb = lds[bf][1];
    short8 af[4], bfr[4];
#pragma unroll
    for (int m = 0; m < 4; ++m)
      af[m] = *(const short8*)(la + (wr * 64 + m * 16 + lr) * 32 + ((hi ^ sw) * 8));
#pragma unroll
    for (int n = 0; n < 4; ++n)
      bfr[n] = *(const short8*)(lb + (wc * 64 + n * 16 + lr) * 32 + ((hi ^ sw) * 8));
#pragma unroll
    for (int m = 0; m < 4; ++m)
#pragma unroll
      for (int n = 0; n < 4; ++n)
        acc[m][n] = __builtin_amdgcn_mfma_f32_16x16x32_bf16(af[m], bfr[n], acc[m][n], 0, 0, 0);
  };

  const int NT = K >> 5;
  stage(0, 0);
  __syncthreads();
  int cur = 0;
  for (int t = 0; t < NT; ++t) {
    if (t + 1 < NT) stage(cur ^ 1, t + 1);
    compute(cur);
    __syncthreads();
    cur ^= 1;
  }

#pragma unroll
  for (int m = 0; m < 4; ++m) {
    int row0 = rb * 128 + wr * 64 + m * 16 + hi * 4;
#pragma unroll
    for (int n = 0; n < 4; ++n) {
      int col = cb * 128 + wc * 64 + n * 16 + lr;
      float bv = bias ? bias[col] : 0.0f;
#pragma unroll
      for (int r = 0; r < 4; ++r) {
        float v = (acc[m][n][r] + bv) * scale;
        if (RELU) v = fmaxf(v, 0.0f);
        if constexpr (sizeof(OutT) == 2)
          C[(size_t)(row0 + r) * ldc + col] = f2bf(v);
        else
          C[(size_t)(row0 + r) * ldc + col] = v;
      }
    }
  }
}

// ---------- fused flash attention ----------
// grid (T/128, B*H); 4 waves; each wave owns 32 q-rows. K-tile/Vt-tile 64x64 bf16
// double-buffered in LDS (XOR swizzle s(r)=r&7 on 16B chunks). Online softmax,
// P round-trips through wave-private LDS (swizzled) to reach A-fragment layout.
__global__ __launch_bounds__(256) void attn_kernel(
    const u16* __restrict__ Q, const u16* __restrict__ KV,
    const u16* __restrict__ Vt, const int* __restrict__ mask,
    u16* __restrict__ CTX) {
  __shared__ __align__(16) u16 kl[2][64 * 64];
  __shared__ __align__(16) u16 vl[2][64 * 64];
  __shared__ __align__(16) u16 pl[4][32 * 64];
  const int lane = threadIdx.x & 63;
  const int wid = threadIdx.x >> 6;
  const int lr = lane & 15, hi = lane >> 4;
  const int qt = blockIdx.x, bh = blockIdx.y;
  const int b = bh >> 4, h = bh & 15;

  short8 qf[2][2];
#pragma unroll
  for (int m = 0; m < 2; ++m)
#pragma unroll
    for (int ks = 0; ks < 2; ++ks) {
      size_t grow = (size_t)(b * 1024 + qt * 128 + wid * 32 + m * 16 + lr);
      qf[m][ks] = *(const short8*)(Q + grow * 1024 + h * 64 + ks * 32 + hi * 8);
    }

  const u16* Kbase = KV + (size_t)(b * 1024) * 2048 + h * 64;  // + key*2048
  const u16* Vbase = Vt + (size_t)(h * 64) * 4096 + b * 1024;  // + dh*4096 + key
  const int sr = lane >> 3;  // staging row within 8
  const int sc = lane & 7;   // staging chunk within 128B row

  auto stage = [&](int bf, int kt) {
#pragma unroll
    for (int j = 0; j < 2; ++j) {
      int r = wid * 16 + j * 8 + sr;
      int cs = sc ^ (r & 7);
      gload16(Kbase + (size_t)(kt * 64 + r) * 2048 + cs * 8,
              &kl[bf][(wid * 16 + j * 8) * 64]);
      gload16(Vbase + (size_t)r * 4096 + kt * 64 + cs * 8,
              &vl[bf][(wid * 16 + j * 8) * 64]);
    }
  };

  float m_run[2][4], l_run[2][4];
  f32x4 O[2][4];
  const f32x4 zero = {0.f, 0.f, 0.f, 0.f};
#pragma unroll
  for (int m = 0; m < 2; ++m) {
#pragma unroll
    for (int r = 0; r < 4; ++r) { m_run[m][r] = -3.0e38f; l_run[m][r] = 0.f; }
#pragma unroll
    for (int d = 0; d < 4; ++d) O[m][d] = zero;
  }

  stage(0, 0);
  __syncthreads();
  int cur = 0;
  for (int kt = 0; kt < 16; ++kt) {
    if (kt + 1 < 16) stage(cur ^ 1, kt + 1);

    short8 kf[4][2];
#pragma unroll
    for (int n = 0; n < 4; ++n) {
      int key = n * 16 + lr;
#pragma unroll
      for (int ks = 0; ks < 2; ++ks) {
        int ch = (hi + 4 * ks) ^ (key & 7);
        kf[n][ks] = *(const short8*)(kl[cur] + key * 64 + ch * 8);
      }
    }
    f32x4 s[2][4];
#pragma unroll
    for (int m = 0; m < 2; ++m)
#pragma unroll
      for (int n = 0; n < 4; ++n) s[m][n] = zero;
#pragma unroll
    for (int ks = 0; ks < 2; ++ks)
#pragma unroll
      for (int m = 0; m < 2; ++m)
#pragma unroll
        for (int n = 0; n < 4; ++n)
          s[m][n] = __builtin_amdgcn_mfma_f32_16x16x32_bf16(qf[m][ks], kf[n][ks], s[m][n], 0, 0, 0);

    bool keep[4];
#pragma unroll
    for (int n = 0; n < 4; ++n)
      keep[n] = mask[b * 1024 + kt * 64 + n * 16 + lr] != 0;

#pragma unroll
    for (int m = 0; m < 2; ++m) {
#pragma unroll
      for (int r = 0; r < 4; ++r) {
        float sv[4];
#pragma unroll
        for (int n = 0; n < 4; ++n) {
          float x = s[m][n][r];
          sv[n] = keep[n] ? x : -3.0e38f;
        }
        float tm = fmaxf(fmaxf(sv[0], sv[1]), fmaxf(sv[2], sv[3]));
        tm = fmaxf(tm, __shfl_xor(tm, 1));
        tm = fmaxf(tm, __shfl_xor(tm, 2));
        tm = fmaxf(tm, __shfl_xor(tm, 4));
        tm = fmaxf(tm, __shfl_xor(tm, 8));
        float mo = m_run[m][r];
        float mn = fmaxf(mo, tm);
        float alpha = __expf(mo - mn);
        m_run[m][r] = mn;
        int prow = m * 16 + hi * 4 + r;
        float ps = 0.f;
        u16 pb[4];
#pragma unroll
        for (int n = 0; n < 4; ++n) {
          float p = __expf(sv[n] - mn);
          ps += p;
          pb[n] = f2bf(p);
        }
        l_run[m][r] = l_run[m][r] * alpha + ps;
#pragma unroll
        for (int d = 0; d < 4; ++d) O[m][d][r] *= alpha;
#pragma unroll
        for (int n = 0; n < 4; ++n) {
          int col = n * 16 + lr;
          int ch = (col >> 3) ^ (prow & 7);
          pl[wid][prow * 64 + ch * 8 + (col & 7)] = pb[n];
        }
      }
    }

#pragma unroll
    for (int ks = 0; ks < 2; ++ks) {
      short8 pa[2], vf[4];
#pragma unroll
      for (int m = 0; m < 2; ++m) {
        int prow = m * 16 + lr;
        int ch = (hi + 4 * ks) ^ (prow & 7);
        pa[m] = *(const short8*)(pl[wid] + prow * 64 + ch * 8);
      }
#pragma unroll
      for (int d = 0; d < 4; ++d) {
        int vrow = d * 16 + lr;
        int ch = (hi + 4 * ks) ^ (vrow & 7);
        vf[d] = *(const short8*)(vl[cur] + vrow * 64 + ch * 8);
      }
#pragma unroll
      for (int m = 0; m < 2; ++m)
#pragma unroll
        for (int d = 0; d < 4; ++d)
          O[m][d] = __builtin_amdgcn_mfma_f32_16x16x32_bf16(pa[m], vf[d], O[m][d], 0, 0, 0);
    }
    __syncthreads();
    cur ^= 1;
  }

#pragma unroll
  for (int m = 0; m < 2; ++m) {
#pragma unroll
    for (int r = 0; r < 4; ++r) {
      float l = l_run[m][r];
      l += __shfl_xor(l, 1);
      l += __shfl_xor(l, 2);
      l += __shfl_xor(l, 4);
      l += __shfl_xor(l, 8);
      float inv = 1.0f / l;
      size_t row = (size_t)(b * 1024 + qt * 128 + wid * 32 + m * 16 + hi * 4 + r);
#pragma unroll
      for (int d = 0; d < 4; ++d)
        CTX[row * 1024 + h * 64 + d * 16 + lr] = f2bf(O[m][d][r] * inv);
    }
  }
}

// ---------- allennlp LayerNorm of (xa + xb): g*(x-mean)/(unbiased_std+eps)+b ----------
__global__ __launch_bounds__(256) void ln_kernel(
    const float* __restrict__ xa, const float* __restrict__ xb,
    const float* __restrict__ g, const float* __restrict__ beta,
    float* __restrict__ of, u16* __restrict__ ob) {
  int row = blockIdx.x;
  int tid = threadIdx.x;
  const float* pa = xa + (size_t)row * 1024;
  const float* pb = xb + (size_t)row * 1024;
  float v[4];
  float s = 0.f, s2 = 0.f;
#pragma unroll
  for (int j = 0; j < 4; ++j) {
    int c = tid + j * 256;
    float x = pa[c] + pb[c];
    v[j] = x; s += x; s2 += x * x;
  }
#pragma unroll
  for (int d = 1; d < 64; d <<= 1) {
    s += __shfl_xor(s, d);
    s2 += __shfl_xor(s2, d);
  }
  __shared__ float red[8];
  int w = tid >> 6, lane = tid & 63;
  if (lane == 0) { red[w] = s; red[4 + w] = s2; }
  __syncthreads();
  s = red[0] + red[1] + red[2] + red[3];
  s2 = red[4] + red[5] + red[6] + red[7];
  float mean = s * (1.0f / 1024.0f);
  float var = fmaxf((s2 - 1024.0f * mean * mean) * (1.0f / 1023.0f), 0.0f);
  float rden = 1.0f / (sqrtf(var) + 1e-6f);
#pragma unroll
  for (int j = 0; j < 4; ++j) {
    int c = tid + j * 256;
    float y = g[c] * (v[j] - mean) * rden + beta[c];
    of[(size_t)row * 1024 + c] = y;
    if (ob) ob[(size_t)row * 1024 + c] = f2bf(y);
  }
}

extern "C" void kernel_launch(void* const* d_in, const int* in_sizes, int n_in,
                              void* d_out, int out_size, void* d_ws, size_t ws_size,
                              hipStream_t stream) {
  const float* src   = (const float*)d_in[0];
  const int*   mask  = (const int*)d_in[1];
  const float* q_w   = (const float*)d_in[2];
  const float* q_b   = (const float*)d_in[3];
  const float* kv_w  = (const float*)d_in[4];
  const float* kv_b  = (const float*)d_in[5];
  const float* out_w = (const float*)d_in[6];
  const float* out_b = (const float*)d_in[7];
  const float* w1    = (const float*)d_in[8];
  const float* b1    = (const float*)d_in[9];
  const float* w2    = (const float*)d_in[10];
  const float* b2    = (const float*)d_in[11];
  const float* g1    = (const float*)d_in[12];
  const float* be1   = (const float*)d_in[13];
  const float* g2    = (const float*)d_in[14];
  const float* be2   = (const float*)d_in[15];
  float* out = (float*)d_out;

  char* ws = (char*)d_ws;
  const size_t MB = 1024 * 1024;
  u16*  Xbf   = (u16*)(ws + 0);         //  8MB (4096x1024)
  u16*  CTX   = (u16*)(ws + 8 * MB);    //  8MB
  u16*  WqT   = (u16*)(ws + 16 * MB);   //  2MB
  u16*  WkvT  = (u16*)(ws + 18 * MB);   //  4MB (2048x1024)
  u16*  WoT   = (u16*)(ws + 22 * MB);   //  2MB
  u16*  W1T   = (u16*)(ws + 24 * MB);   //  8MB (4096x1024)
  u16*  W2T   = (u16*)(ws + 32 * MB);   //  8MB (1024x4096)
  u16*  Qbf   = (u16*)(ws + 40 * MB);   //  8MB
  u16*  KVbf  = (u16*)(ws + 48 * MB);   // 16MB (4096x2048)
  u16*  Vt    = (u16*)(ws + 64 * MB);   //  8MB (1024x4096)
  u16*  F1b   = (u16*)(ws + 40 * MB);   // 32MB (4096x4096), aliases Qbf/KVbf/Vt (dead)
  float* AOUT = (float*)(ws + 72 * MB); // 16MB
  float* OUT1F= (float*)(ws + 88 * MB); // 16MB
  u16*  OUT1B = (u16*)(ws + 104 * MB);  //  8MB
  float* F2F  = (float*)(ws + 0);       // 16MB, aliases Xbf+CTX (dead)

  // 1. cast activations
  cast_f32_bf16_kernel<<<dim3(4096), dim3(256), 0, stream>>>(src, Xbf, 1024 * 1024);
  // 2. weight transpose+cast to [out][in] bf16
  transpose_to_bf16_kernel<float><<<dim3(32, 32), dim3(32, 8), 0, stream>>>(q_w, 1024, 0, WqT, 1024);
  transpose_to_bf16_kernel<float><<<dim3(64, 32), dim3(32, 8), 0, stream>>>(kv_w, 2048, 0, WkvT, 1024);
  transpose_to_bf16_kernel<float><<<dim3(32, 32), dim3(32, 8), 0, stream>>>(out_w, 1024, 0, WoT, 1024);
  transpose_to_bf16_kernel<float><<<dim3(128, 32), dim3(32, 8), 0, stream>>>(w1, 4096, 0, W1T, 1024);
  transpose_to_bf16_kernel<float><<<dim3(32, 128), dim3(32, 8), 0, stream>>>(w2, 1024, 0, W2T, 4096);
  // 3. Q = (X @ q_w + q_b) / 8   (scale folded into epilogue)
  gemm_bt_kernel<u16, false><<<dim3(8, 32), dim3(256), 0, stream>>>(Xbf, 1024, WqT, 1024, q_b, Qbf, 1024, 1024, 0.125f);
  // 4. KV = X @ kv_w + kv_b
  gemm_bt_kernel<u16, false><<<dim3(16, 32), dim3(256), 0, stream>>>(Xbf, 1024, WkvT, 1024, kv_b, KVbf, 2048, 1024, 1.0f);
  // 5. Vt[dh][m] = KV[m][1024+dh]
  transpose_to_bf16_kernel<u16><<<dim3(32, 128), dim3(32, 8), 0, stream>>>(KVbf, 2048, 1024, Vt, 4096);
  // 6. fused attention -> CTX
  attn_kernel<<<dim3(8, 64), dim3(256), 0, stream>>>(Qbf, KVbf, Vt, mask, CTX);
  // 7. attn_out = CTX @ out_w + out_b
  gemm_bt_kernel<float, false><<<dim3(8, 32), dim3(256), 0, stream>>>(CTX, 1024, WoT, 1024, out_b, AOUT, 1024, 1024, 1.0f);
  // 8. out1 = LN(src + attn_out)
  ln_kernel<<<dim3(4096), dim3(256), 0, stream>>>(src, AOUT, g1, be1, OUT1F, OUT1B);
  // 9. ffn1 = relu(out1 @ w1 + b1)
  gemm_bt_kernel<u16, true><<<dim3(32, 32), dim3(256), 0, stream>>>(OUT1B, 1024, W1T, 1024, b1, F1b, 4096, 1024, 1.0f);
  // 10. ffn2 = ffn1 @ w2 + b2
  gemm_bt_kernel<float, false><<<dim3(8, 32), dim3(256), 0, stream>>>(F1b, 4096, W2T, 4096, b2, F2F, 1024, 4096, 1.0f);
  // 11. out = LN(out1 + ffn2)
  ln_kernel<<<dim3(4096), dim3(256), 0, stream>>>(OUT1F, F2F, g2, be2, out, nullptr);
  (void)in_sizes; (void)n_in; (void)out_size; (void)ws_size;
}

// Round 2
// 378.949 us; speedup vs baseline: 1.1063x; 1.1063x over previous
//
#include <hip/hip_runtime.h>

#define DEV __device__ __forceinline__

typedef unsigned short u16;
typedef __attribute__((ext_vector_type(4))) float f32x4;
typedef __attribute__((ext_vector_type(8))) short short8;

// ---------- bf16 helpers (manual, RNE) ----------
DEV u16 f2bf(float f) {
  union { float f; unsigned u; } c; c.f = f;
  unsigned u = c.u;
  unsigned r = (u + 0x7FFFu + ((u >> 16) & 1u)) >> 16;
  return (u16)r;
}
DEV float bf2f(u16 h) {
  union { unsigned u; float f; } c; c.u = ((unsigned)h) << 16;
  return c.f;
}

// ---------- async global -> LDS (16B per lane) ----------
DEV void gload16(const void* g, void* l) {
  __builtin_amdgcn_global_load_lds(
      (__attribute__((address_space(1))) void*)(g),
      (__attribute__((address_space(3))) void*)(l), 16, 0, 0);
}

// ---------- cast fp32 -> bf16 (vectorized) ----------
__global__ __launch_bounds__(256) void cast_f32_bf16_kernel(
    const float* __restrict__ in, u16* __restrict__ out, int n4) {
  int i = blockIdx.x * blockDim.x + threadIdx.x;
  if (i >= n4) return;
  float4 v = reinterpret_cast<const float4*>(in)[i];
  ushort4 o;
  o.x = f2bf(v.x); o.y = f2bf(v.y); o.z = f2bf(v.z); o.w = f2bf(v.w);
  reinterpret_cast<ushort4*>(out)[i] = o;
}

// ---------- tiled transpose (+cast) : out[c][r] = bf16(in[r][c+col_off]) ----------
template <typename TIN>
__global__ __launch_bounds__(256) void transpose_to_bf16_kernel(
    const TIN* __restrict__ in, int ld_in, int col_off,
    u16* __restrict__ out, int ld_out) {
  __shared__ float tile[32][33];
  int c0 = blockIdx.x * 32, r0 = blockIdx.y * 32;
  int tx = threadIdx.x, ty = threadIdx.y;
#pragma unroll
  for (int j = 0; j < 4; ++j) {
    int r = r0 + ty + j * 8;
    TIN raw = in[(size_t)r * ld_in + col_off + c0 + tx];
    float v;
    if constexpr (sizeof(TIN) == 4) v = (float)raw;
    else v = bf2f((u16)raw);
    tile[ty + j * 8][tx] = v;
  }
  __syncthreads();
#pragma unroll
  for (int j = 0; j < 4; ++j) {
    out[(size_t)(c0 + ty + j * 8) * ld_out + r0 + tx] = f2bf(tile[tx][ty + j * 8]);
  }
}

// ---------- GEMM: C[M,N] = A[M,K] * Bt[N,K]^T (+bias)*scale, optional ReLU ----------
// 128x128 tile, BK=32, 4 waves (2x2), mfma_f32_16x16x32_bf16, double-buffered
// global_load_lds staging with XOR chunk-swizzle (s(r) = (r>>1)&3 on 16B chunks).
// Split-K via blockIdx.z: chunk z reads A/Bt at k-offset z*K, writes C + z*c_off.
// Per-column epilogue: col < split -> bias[col], scale; else bias2[col-split], 1.0.
template <typename OutT, bool RELU>
__global__ __launch_bounds__(256) void gemm_bt_kernel(
    const u16* __restrict__ A, int lda,
    const u16* __restrict__ Bt, int ldb,
    const float* __restrict__ bias, const float* __restrict__ bias2, int split,
    OutT* __restrict__ C, int ldc, size_t c_off,
    int K, float scale) {
  __shared__ __align__(16) u16 lds[2][2][128 * 32];
  const int lane = threadIdx.x & 63;
  const int wid = threadIdx.x >> 6;
  const int wr = wid >> 1, wc = wid & 1;
  const int lr = lane & 15, hi = lane >> 4;
  const int rb = blockIdx.y, cb = blockIdx.x;
  const int z = blockIdx.z;
  const int r_in = lane >> 2;  // staging: row within 16-row group
  const int c_in = lane & 3;   // staging: 16B chunk within 64B row

  const u16* Abase = A + (size_t)(rb * 128) * lda + (size_t)z * K;
  const u16* Bbase = Bt + (size_t)(cb * 128) * ldb + (size_t)z * K;
  if (z != 0) bias = nullptr;   // bias added once (chunk 0)
  C += (size_t)z * c_off;

  f32x4 acc[4][4];
  const f32x4 zero = {0.f, 0.f, 0.f, 0.f};
#pragma unroll
  for (int m = 0; m < 4; ++m)
#pragma unroll
    for (int n = 0; n < 4; ++n) acc[m][n] = zero;

  auto stage = [&](int bf, int t) {
#pragma unroll
    for (int j = 0; j < 2; ++j) {
      int r = wid * 16 + j * 64 + r_in;
      int csrc = c_in ^ ((r >> 1) & 3);
      gload16(Abase + (size_t)r * lda + t * 32 + csrc * 8,
              &lds[bf][0][(wid * 16 + j * 64) * 32]);
      gload16(Bbase + (size_t)r * ldb + t * 32 + csrc * 8,
              &lds[bf][1][(wid * 16 + j * 64) * 32]);
    }
  };

  const int sw = (lr >> 1) & 3;
  auto compute = [&](int bf) {
    const u16* la = lds[bf][0];
    const u16* lb = lds[bf][1];
    short8 af[4], bfr[4];
#pragma unroll
    for (int m = 0; m < 4; ++m)
      af[m] = *(const short8*)(la + (wr * 64 + m * 16 + lr) * 32 + ((hi ^ sw) * 8));
#pragma unroll
    for (int n = 0; n < 4; ++n)
      bfr[n] = *(const short8*)(lb + (wc * 64 + n * 16 + lr) * 32 + ((hi ^ sw) * 8));
#pragma unroll
    for (int m = 0; m < 4; ++m)
#pragma unroll
      for (int n = 0; n < 4; ++n)
        acc[m][n] = __builtin_amdgcn_mfma_f32_16x16x32_bf16(af[m], bfr[n], acc[m][n], 0, 0, 0);
  };

  const int NT = K >> 5;
  stage(0, 0);
  __syncthreads();
  int cur = 0;
  for (int t = 0; t < NT; ++t) {
    if (t + 1 < NT) stage(cur ^ 1, t + 1);
    compute(cur);
    __syncthreads();
    cur ^= 1;
  }

#pragma unroll
  for (int m = 0; m < 4; ++m) {
    int row0 = rb * 128 + wr * 64 + m * 16 + hi * 4;
#pragma unroll
    for (int n = 0; n < 4; ++n) {
      int col = cb * 128 + wc * 64 + n * 16 + lr;
      float bv = 0.0f, sc = scale;
      if (bias) {
        if (col < split) bv = bias[col];
        else { bv = bias2[col - split]; sc = 1.0f; }
      }
#pragma unroll
      for (int r = 0; r < 4; ++r) {
        float v = (acc[m][n][r] + bv) * sc;
        if (RELU) v = fmaxf(v, 0.0f);
        if constexpr (sizeof(OutT) == 2)
          C[(size_t)(row0 + r) * ldc + col] = f2bf(v);
        else
          C[(size_t)(row0 + r) * ldc + col] = v;
      }
    }
  }
}

// ---------- fused flash attention ----------
// grid (B*H, T/128): blockIdx.x = head (fastest) so the 8 q-blocks of a head
// land on the SAME XCD (lid = qt*64+bh, XCD = bh%8) -> K/V stays L2-resident.
// 4 waves; each wave owns 32 q-rows. K-tile/Vt-tile 64x64 bf16 double-buffered
// in LDS (XOR swizzle s(r)=r&7 on 16B chunks). Online softmax; P round-trips
// through wave-private LDS. Q/K read from fused QKV buffer (ld 3072).
__global__ __launch_bounds__(256) void attn_kernel(
    const u16* __restrict__ QKV, const u16* __restrict__ Vt,
    const int* __restrict__ mask, u16* __restrict__ CTX) {
  __shared__ __align__(16) u16 kl[2][64 * 64];
  __shared__ __align__(16) u16 vl[2][64 * 64];
  __shared__ __align__(16) u16 pl[4][32 * 64];
  const int lane = threadIdx.x & 63;
  const int wid = threadIdx.x >> 6;
  const int lr = lane & 15, hi = lane >> 4;
  const int bh = blockIdx.x, qt = blockIdx.y;
  const int b = bh >> 4, h = bh & 15;

  short8 qf[2][2];
#pragma unroll
  for (int m = 0; m < 2; ++m)
#pragma unroll
    for (int ks = 0; ks < 2; ++ks) {
      size_t grow = (size_t)(b * 1024 + qt * 128 + wid * 32 + m * 16 + lr);
      qf[m][ks] = *(const short8*)(QKV + grow * 3072 + h * 64 + ks * 32 + hi * 8);
    }

  // hoisted per-lane key mask: bit (kt*4+n) = mask[key = kt*64 + n*16 + lr]
  unsigned long long keepm = 0ull;
#pragma unroll
  for (int kt = 0; kt < 16; ++kt)
#pragma unroll
    for (int n = 0; n < 4; ++n)
      if (mask[b * 1024 + kt * 64 + n * 16 + lr] != 0)
        keepm |= (1ull << (kt * 4 + n));

  const u16* Kbase = QKV + (size_t)(b * 1024) * 3072 + 1024 + h * 64;  // + key*3072
  const u16* Vbase = Vt + (size_t)(h * 64) * 4096 + b * 1024;          // + dh*4096 + key
  const int sr = lane >> 3;  // staging row within 8
  const int sc = lane & 7;   // staging chunk within 128B row

  auto stage = [&](int bf, int kt) {
#pragma unroll
    for (int j = 0; j < 2; ++j) {
      int r = wid * 16 + j * 8 + sr;
      int cs = sc ^ (r & 7);
      gload16(Kbase + (size_t)(kt * 64 + r) * 3072 + cs * 8,
              &kl[bf][(wid * 16 + j * 8) * 64]);
      gload16(Vbase + (size_t)r * 4096 + kt * 64 + cs * 8,
              &vl[bf][(wid * 16 + j * 8) * 64]);
    }
  };

  float m_run[2][4], l_run[2][4];
  f32x4 O[2][4];
  const f32x4 zero = {0.f, 0.f, 0.f, 0.f};
#pragma unroll
  for (int m = 0; m < 2; ++m) {
#pragma unroll
    for (int r = 0; r < 4; ++r) { m_run[m][r] = -3.0e38f; l_run[m][r] = 0.f; }
#pragma unroll
    for (int d = 0; d < 4; ++d) O[m][d] = zero;
  }

  stage(0, 0);
  __syncthreads();
  int cur = 0;
  for (int kt = 0; kt < 16; ++kt) {
    if (kt + 1 < 16) stage(cur ^ 1, kt + 1);

    short8 kf[4][2];
#pragma unroll
    for (int n = 0; n < 4; ++n) {
      int key = n * 16 + lr;
#pragma unroll
      for (int ks = 0; ks < 2; ++ks) {
        int ch = (hi + 4 * ks) ^ (key & 7);
        kf[n][ks] = *(const short8*)(kl[cur] + key * 64 + ch * 8);
      }
    }
    f32x4 s[2][4];
#pragma unroll
    for (int m = 0; m < 2; ++m)
#pragma unroll
      for (int n = 0; n < 4; ++n) s[m][n] = zero;
#pragma unroll
    for (int ks = 0; ks < 2; ++ks)
#pragma unroll
      for (int m = 0; m < 2; ++m)
#pragma unroll
        for (int n = 0; n < 4; ++n)
          s[m][n] = __builtin_amdgcn_mfma_f32_16x16x32_bf16(qf[m][ks], kf[n][ks], s[m][n], 0, 0, 0);

    bool keep[4];
#pragma unroll
    for (int n = 0; n < 4; ++n)
      keep[n] = (keepm >> (kt * 4 + n)) & 1ull;

#pragma unroll
    for (int m = 0; m < 2; ++m) {
#pragma unroll
      for (int r = 0; r < 4; ++r) {
        float sv[4];
#pragma unroll
        for (int n = 0; n < 4; ++n) {
          float x = s[m][n][r];
          sv[n] = keep[n] ? x : -3.0e38f;
        }
        float tm = fmaxf(fmaxf(sv[0], sv[1]), fmaxf(sv[2], sv[3]));
        tm = fmaxf(tm, __shfl_xor(tm, 1));
        tm = fmaxf(tm, __shfl_xor(tm, 2));
        tm = fmaxf(tm, __shfl_xor(tm, 4));
        tm = fmaxf(tm, __shfl_xor(tm, 8));
        float mo = m_run[m][r];
        float mn = fmaxf(mo, tm);
        float alpha = __expf(mo - mn);
        m_run[m][r] = mn;
        int prow = m * 16 + hi * 4 + r;
        float ps = 0.f;
        u16 pb[4];
#pragma unroll
        for (int n = 0; n < 4; ++n) {
          float p = __expf(sv[n] - mn);
          ps += p;
          pb[n] = f2bf(p);
        }
        l_run[m][r] = l_run[m][r] * alpha + ps;
#pragma unroll
        for (int d = 0; d < 4; ++d) O[m][d][r] *= alpha;
#pragma unroll
        for (int n = 0; n < 4; ++n) {
          int col = n * 16 + lr;
          int ch = (col >> 3) ^ (prow & 7);
          pl[wid][prow * 64 + ch * 8 + (col & 7)] = pb[n];
        }
      }
    }

#pragma unroll
    for (int ks = 0; ks < 2; ++ks) {
      short8 pa[2], vf[4];
#pragma unroll
      for (int m = 0; m < 2; ++m) {
        int prow = m * 16 + lr;
        int ch = (hi + 4 * ks) ^ (prow & 7);
        pa[m] = *(const short8*)(pl[wid] + prow * 64 + ch * 8);
      }
#pragma unroll
      for (int d = 0; d < 4; ++d) {
        int vrow = d * 16 + lr;
        int ch = (hi + 4 * ks) ^ (vrow & 7);
        vf[d] = *(const short8*)(vl[cur] + vrow * 64 + ch * 8);
      }
#pragma unroll
      for (int m = 0; m < 2; ++m)
#pragma unroll
        for (int d = 0; d < 4; ++d)
          O[m][d] = __builtin_amdgcn_mfma_f32_16x16x32_bf16(pa[m], vf[d], O[m][d], 0, 0, 0);
    }
    __syncthreads();
    cur ^= 1;
  }

#pragma unroll
  for (int m = 0; m < 2; ++m) {
#pragma unroll
    for (int r = 0; r < 4; ++r) {
      float l = l_run[m][r];
      l += __shfl_xor(l, 1);
      l += __shfl_xor(l, 2);
      l += __shfl_xor(l, 4);
      l += __shfl_xor(l, 8);
      float inv = 1.0f / l;
      size_t row = (size_t)(b * 1024 + qt * 128 + wid * 32 + m * 16 + hi * 4 + r);
#pragma unroll
      for (int d = 0; d < 4; ++d)
        CTX[row * 1024 + h * 64 + d * 16 + lr] = f2bf(O[m][d][r] * inv);
    }
  }
}

// ---------- allennlp LayerNorm of (xa+xb[+xc]): g*(x-mean)/(unbiased_std+eps)+b ----------
__global__ __launch_bounds__(256) void ln_kernel(
    const float* __restrict__ xa, const float* __restrict__ xb,
    const float* __restrict__ xc,
    const float* __restrict__ g, const float* __restrict__ beta,
    float* __restrict__ of, u16* __restrict__ ob) {
  int row = blockIdx.x;
  int tid = threadIdx.x;
  const float* pa = xa + (size_t)row * 1024;
  const float* pb = xb + (size_t)row * 1024;
  const float* pc = xc ? xc + (size_t)row * 1024 : nullptr;
  float v[4];
  float s = 0.f, s2 = 0.f;
#pragma unroll
  for (int j = 0; j < 4; ++j) {
    int c = tid + j * 256;
    float x = pa[c] + pb[c];
    if (pc) x += pc[c];
    v[j] = x; s += x; s2 += x * x;
  }
#pragma unroll
  for (int d = 1; d < 64; d <<= 1) {
    s += __shfl_xor(s, d);
    s2 += __shfl_xor(s2, d);
  }
  __shared__ float red[8];
  int w = tid >> 6, lane = tid & 63;
  if (lane == 0) { red[w] = s; red[4 + w] = s2; }
  __syncthreads();
  s = red[0] + red[1] + red[2] + red[3];
  s2 = red[4] + red[5] + red[6] + red[7];
  float mean = s * (1.0f / 1024.0f);
  float var = fmaxf((s2 - 1024.0f * mean * mean) * (1.0f / 1023.0f), 0.0f);
  float rden = 1.0f / (sqrtf(var) + 1e-6f);
#pragma unroll
  for (int j = 0; j < 4; ++j) {
    int c = tid + j * 256;
    float y = g[c] * (v[j] - mean) * rden + beta[c];
    of[(size_t)row * 1024 + c] = y;
    if (ob) ob[(size_t)row * 1024 + c] = f2bf(y);
  }
}

extern "C" void kernel_launch(void* const* d_in, const int* in_sizes, int n_in,
                              void* d_out, int out_size, void* d_ws, size_t ws_size,
                              hipStream_t stream) {
  const float* src   = (const float*)d_in[0];
  const int*   mask  = (const int*)d_in[1];
  const float* q_w   = (const float*)d_in[2];
  const float* q_b   = (const float*)d_in[3];
  const float* kv_w  = (const float*)d_in[4];
  const float* kv_b  = (const float*)d_in[5];
  const float* out_w = (const float*)d_in[6];
  const float* out_b = (const float*)d_in[7];
  const float* w1    = (const float*)d_in[8];
  const float* b1    = (const float*)d_in[9];
  const float* w2    = (const float*)d_in[10];
  const float* b2    = (const float*)d_in[11];
  const float* g1    = (const float*)d_in[12];
  const float* be1   = (const float*)d_in[13];
  const float* g2    = (const float*)d_in[14];
  const float* be2   = (const float*)d_in[15];
  float* out = (float*)d_out;

  char* ws = (char*)d_ws;
  const size_t MB = 1024 * 1024;
  const int BIG = 1 << 30;
  u16*  Xbf   = (u16*)(ws + 0);          //  8MB (4096x1024)
  u16*  CTX   = (u16*)(ws + 8 * MB);     //  8MB
  u16*  WqkvT = (u16*)(ws + 16 * MB);    //  6MB (3072x1024): q rows 0-1023, kv rows 1024-3071
  u16*  WoT   = (u16*)(ws + 22 * MB);    //  2MB
  u16*  W1T   = (u16*)(ws + 24 * MB);    //  8MB (4096x1024)
  u16*  W2T   = (u16*)(ws + 32 * MB);    //  8MB (1024x4096)
  u16*  QKV   = (u16*)(ws + 40 * MB);    // 24MB (4096x3072)
  u16*  Vt    = (u16*)(ws + 64 * MB);    //  8MB (1024x4096)
  u16*  F1b   = (u16*)(ws + 40 * MB);    // 32MB (4096x4096), aliases QKV+Vt (dead after attn)
  float* AOUT = (float*)(ws + 72 * MB);  // 16MB
  float* OUT1F= (float*)(ws + 88 * MB);  // 16MB
  u16*  OUT1B = (u16*)(ws + 104 * MB);   //  8MB
  float* P0   = (float*)(ws + 0);        // 16MB, FFN2 partial (aliases Xbf+CTX, dead)
  float* P1   = (float*)(ws + 72 * MB);  // 16MB, FFN2 partial (aliases AOUT, dead)

  // 1. cast activations
  cast_f32_bf16_kernel<<<dim3(4096), dim3(256), 0, stream>>>(src, Xbf, 1024 * 1024);
  // 2. weight transpose+cast to [out][in] bf16 (q and kv into one contiguous buffer)
  transpose_to_bf16_kernel<float><<<dim3(32, 32), dim3(32, 8), 0, stream>>>(q_w, 1024, 0, WqkvT, 1024);
  transpose_to_bf16_kernel<float><<<dim3(64, 32), dim3(32, 8), 0, stream>>>(kv_w, 2048, 0, WqkvT + (size_t)1024 * 1024, 1024);
  transpose_to_bf16_kernel<float><<<dim3(32, 32), dim3(32, 8), 0, stream>>>(out_w, 1024, 0, WoT, 1024);
  transpose_to_bf16_kernel<float><<<dim3(128, 32), dim3(32, 8), 0, stream>>>(w1, 4096, 0, W1T, 1024);
  transpose_to_bf16_kernel<float><<<dim3(32, 128), dim3(32, 8), 0, stream>>>(w2, 1024, 0, W2T, 4096);
  // 3. QKV = X @ [q_w|kv_w] + [q_b|kv_b]; Q columns scaled by 1/8
  gemm_bt_kernel<u16, false><<<dim3(24, 32), dim3(256), 0, stream>>>(
      Xbf, 1024, WqkvT, 1024, q_b, kv_b, 1024, QKV, 3072, 0, 1024, 0.125f);
  // 4. Vt[dh][m] = QKV[m][2048+dh]
  transpose_to_bf16_kernel<u16><<<dim3(32, 128), dim3(32, 8), 0, stream>>>(QKV, 3072, 2048, Vt, 4096);
  // 5. fused attention -> CTX  (grid x = head so each head's q-blocks share an XCD)
  attn_kernel<<<dim3(64, 8), dim3(256), 0, stream>>>(QKV, Vt, mask, CTX);
  // 6. attn_out = CTX @ out_w + out_b
  gemm_bt_kernel<float, false><<<dim3(8, 32), dim3(256), 0, stream>>>(
      CTX, 1024, WoT, 1024, out_b, nullptr, BIG, AOUT, 1024, 0, 1024, 1.0f);
  // 7. out1 = LN(src + attn_out)
  ln_kernel<<<dim3(4096), dim3(256), 0, stream>>>(src, AOUT, nullptr, g1, be1, OUT1F, OUT1B);
  // 8. ffn1 = relu(out1 @ w1 + b1)
  gemm_bt_kernel<u16, true><<<dim3(32, 32), dim3(256), 0, stream>>>(
      OUT1B, 1024, W1T, 1024, b1, nullptr, BIG, F1b, 4096, 0, 1024, 1.0f);
  // 9. ffn2 partials: split-K=2 (z-chunks), chunk0 adds bias; P0 @ws+0, P1 @ws+72MB
  gemm_bt_kernel<float, false><<<dim3(8, 32, 2), dim3(256), 0, stream>>>(
      F1b, 4096, W2T, 4096, b2, nullptr, BIG, P0, 1024,
      (size_t)(P1 - P0), 2048, 1.0f);
  // 10. out = LN(out1 + P0 + P1)
  ln_kernel<<<dim3(4096), dim3(256), 0, stream>>>(OUT1F, P0, P1, g2, be2, out, nullptr);
  (void)in_sizes; (void)n_in; (void)out_size; (void)ws_size;
}

// Round 3
// 347.204 us; speedup vs baseline: 1.2074x; 1.0914x over previous
//
#include <hip/hip_runtime.h>

#define DEV __device__ __forceinline__
#define SB0 __builtin_amdgcn_sched_barrier(0)

typedef unsigned short u16;
typedef __attribute__((ext_vector_type(4))) float f32x4;
typedef __attribute__((ext_vector_type(8))) short short8;

DEV u16 f2bf(float f) {
  union { float f; unsigned u; } c; c.f = f;
  unsigned u = c.u;
  unsigned r = (u + 0x7FFFu + ((u >> 16) & 1u)) >> 16;
  return (u16)r;
}
DEV float bf2f(u16 h) {
  union { unsigned u; float f; } c; c.u = ((unsigned)h) << 16;
  return c.f;
}

DEV void gload16(const void* g, void* l) {
  __builtin_amdgcn_global_load_lds(
      (__attribute__((address_space(1))) void*)(g),
      (__attribute__((address_space(3))) void*)(l), 16, 0, 0);
}
DEV void vmc8() { asm volatile("s_waitcnt vmcnt(8)" ::: "memory"); SB0; }
DEV void vmc0() { asm volatile("s_waitcnt vmcnt(0)" ::: "memory"); SB0; }

// ---------- merged prep: cast src->bf16 + 5 weight transposes ----------
__global__ __launch_bounds__(256) void prep_kernel(
    const float* __restrict__ src, const float* __restrict__ q_w,
    const float* __restrict__ kv_w, const float* __restrict__ out_w,
    const float* __restrict__ w1, const float* __restrict__ w2,
    u16* __restrict__ Xbf, u16* __restrict__ WqkvT, u16* __restrict__ WoT,
    u16* __restrict__ W1T, u16* __restrict__ W2T) {
  __shared__ float tile[32 * 33];
  int bb = blockIdx.x, tid = threadIdx.x;
  if (bb < 4096) {  // cast 4M floats
    int i = bb * 256 + tid;
    float4 v = reinterpret_cast<const float4*>(src)[i];
    ushort4 o;
    o.x = f2bf(v.x); o.y = f2bf(v.y); o.z = f2bf(v.z); o.w = f2bf(v.w);
    reinterpret_cast<ushort4*>(Xbf)[i] = o;
    return;
  }
  const float* in; u16* outp; int ld_in, ld_out, bx, by;
  if (bb < 5120)       { int t = bb - 4096;  in = q_w;   outp = WqkvT; ld_in = 1024; ld_out = 1024; bx = t & 31;  by = t >> 5; }
  else if (bb < 7168)  { int t = bb - 5120;  in = kv_w;  outp = WqkvT + (size_t)1024 * 1024; ld_in = 2048; ld_out = 1024; bx = t & 63;  by = t >> 6; }
  else if (bb < 8192)  { int t = bb - 7168;  in = out_w; outp = WoT;   ld_in = 1024; ld_out = 1024; bx = t & 31;  by = t >> 5; }
  else if (bb < 12288) { int t = bb - 8192;  in = w1;    outp = W1T;   ld_in = 4096; ld_out = 1024; bx = t & 127; by = t >> 7; }
  else                 { int t = bb - 12288; in = w2;    outp = W2T;   ld_in = 1024; ld_out = 4096; bx = t & 31;  by = t >> 5; }
  int tx = tid & 31, ty = tid >> 5;
  int c0 = bx * 32, r0 = by * 32;
#pragma unroll
  for (int j = 0; j < 4; ++j)
    tile[(ty + j * 8) * 33 + tx] = in[(size_t)(r0 + ty + j * 8) * ld_in + c0 + tx];
  __syncthreads();
#pragma unroll
  for (int j = 0; j < 4; ++j)
    outp[(size_t)(c0 + ty + j * 8) * ld_out + r0 + tx] = f2bf(tile[tx * 33 + ty + j * 8]);
}

// ---------- tiled transpose (+cast) for u16 (Vt extraction) ----------
__global__ __launch_bounds__(256) void transpose_u16_kernel(
    const u16* __restrict__ in, int ld_in, int col_off,
    u16* __restrict__ out, int ld_out) {
  __shared__ float tile[32][33];
  int c0 = blockIdx.x * 32, r0 = blockIdx.y * 32;
  int tx = threadIdx.x, ty = threadIdx.y;
#pragma unroll
  for (int j = 0; j < 4; ++j) {
    int r = r0 + ty + j * 8;
    tile[ty + j * 8][tx] = bf2f(in[(size_t)r * ld_in + col_off + c0 + tx]);
  }
  __syncthreads();
#pragma unroll
  for (int j = 0; j < 4; ++j)
    out[(size_t)(c0 + ty + j * 8) * ld_out + r0 + tx] = f2bf(tile[tx][ty + j * 8]);
}

// ---------- ring-4 pipelined GEMM: C[M,N] = A[M,K] * Bt[N,K]^T ----------
// BM=BN tile; BK=32; NWARP waves (2 x NWARP/2). 4 LDS slots, 3 K-tiles
// prefetched ahead via global_load_lds(16B); one raw s_barrier + counted
// vmcnt(8) per K-tile (never drains the pipeline in steady state).
// XOR chunk-swizzle swz(r)=(r>>1)&3 on 16B chunks (measured 0 conflicts).
// Per-column epilogue: col<split -> bias*scale else bias2*1.0; optional ReLU.
template <int BM, int NWARP, typename OutT, bool RELU>
__global__ __launch_bounds__(NWARP * 64, 2) void gemm_ring_kernel(
    const u16* __restrict__ A, int lda,
    const u16* __restrict__ Bt, int ldb,
    const float* __restrict__ bias, const float* __restrict__ bias2, int split,
    OutT* __restrict__ C, int ldc, int K, float scale) {
  constexpr int MT = BM / 32;        // m-tiles per wave
  constexpr int PWR = BM / 2;        // rows per wave
  constexpr int WN = NWARP / 2;      // waves along N
  constexpr int SLOT = 2 * BM * 32;  // u16 elems per ring slot (A|B)
  __shared__ __align__(16) u16 ring[4][SLOT];

  const int tid = threadIdx.x;
  const int lane = tid & 63, wid = tid >> 6;
  const int wr = wid / WN, wc = wid % WN;
  const int lr = lane & 15, hi = lane >> 4;

  // bijective XCD-chunked swizzle (m204): consecutive lid -> same XCD
  const int gx = gridDim.x;
  const int nwg = gx * gridDim.y;
  const int orig = blockIdx.y * gx + blockIdx.x;
  const int q = nwg >> 3, r8 = nwg & 7, xcd = orig & 7, oo = orig >> 3;
  const int lid = (xcd < r8 ? xcd * (q + 1) : r8 * (q + 1) + (xcd - r8) * q) + oo;
  const int rb = lid / gx, cb = lid % gx;

  const u16* Abase = A + (size_t)rb * BM * lda;
  const u16* Bbase = Bt + (size_t)cb * BM * ldb;

  auto stage = [&](int slot, int kt) {
#pragma unroll
    for (int j = 0; j < 2; ++j) {
      int ch = wid * 2 + j;
      int row = ch * 16 + (lane >> 2);
      int cs = (lane & 3) ^ ((row >> 1) & 3);
      gload16(Abase + (size_t)row * lda + kt * 32 + cs * 8, &ring[slot][ch * 512]);
      gload16(Bbase + (size_t)row * ldb + kt * 32 + cs * 8, &ring[slot][BM * 32 + ch * 512]);
    }
  };

  f32x4 acc[MT][4];
  const f32x4 zero = {0.f, 0.f, 0.f, 0.f};
#pragma unroll
  for (int m = 0; m < MT; ++m)
#pragma unroll
    for (int n = 0; n < 4; ++n) acc[m][n] = zero;

  const int NT = K >> 5;
  stage(0, 0); stage(1, 1); stage(2, 2);
  vmc8();
  __builtin_amdgcn_s_barrier(); SB0;

  const int sw = (lr >> 1) & 3;
  for (int k = 0; k < NT; ++k) {
    const u16* la = &ring[k & 3][0];
    const u16* lb = &ring[k & 3][BM * 32];
    short8 bf[4], af[MT];
#pragma unroll
    for (int n = 0; n < 4; ++n)
      bf[n] = *(const short8*)(lb + (wc * 64 + n * 16 + lr) * 32 + ((hi ^ sw) * 8));
#pragma unroll
    for (int m = 0; m < MT; ++m)
      af[m] = *(const short8*)(la + (wr * PWR + m * 16 + lr) * 32 + ((hi ^ sw) * 8));
    if (k + 3 < NT) stage((k + 3) & 3, k + 3);
    __builtin_amdgcn_s_setprio(1);
#pragma unroll
    for (int m = 0; m < MT; ++m)
#pragma unroll
      for (int n = 0; n < 4; ++n)
        acc[m][n] = __builtin_amdgcn_mfma_f32_16x16x32_bf16(af[m], bf[n], acc[m][n], 0, 0, 0);
    __builtin_amdgcn_s_setprio(0);
    if (k + 4 < NT) vmc8();
    else if (k + 1 < NT) vmc0();
    __builtin_amdgcn_s_barrier(); SB0;
  }

#pragma unroll
  for (int m = 0; m < MT; ++m) {
    int row0 = rb * BM + wr * PWR + m * 16 + hi * 4;
#pragma unroll
    for (int n = 0; n < 4; ++n) {
      int col = cb * BM + wc * 64 + n * 16 + lr;
      float bv = 0.0f, sc = scale;
      if (col < split) bv = bias[col];
      else { bv = bias2[col - split]; sc = 1.0f; }
#pragma unroll
      for (int r = 0; r < 4; ++r) {
        float v = (acc[m][n][r] + bv) * sc;
        if (RELU) v = fmaxf(v, 0.0f);
        if constexpr (sizeof(OutT) == 2)
          C[(size_t)(row0 + r) * ldc + col] = f2bf(v);
        else
          C[(size_t)(row0 + r) * ldc + col] = v;
      }
    }
  }
}

// ---------- fused flash attention (unchanged from R2) ----------
__global__ __launch_bounds__(256) void attn_kernel(
    const u16* __restrict__ QKV, const u16* __restrict__ Vt,
    const int* __restrict__ mask, u16* __restrict__ CTX) {
  __shared__ __align__(16) u16 kl[2][64 * 64];
  __shared__ __align__(16) u16 vl[2][64 * 64];
  __shared__ __align__(16) u16 pl[4][32 * 64];
  const int lane = threadIdx.x & 63;
  const int wid = threadIdx.x >> 6;
  const int lr = lane & 15, hi = lane >> 4;
  const int bh = blockIdx.x, qt = blockIdx.y;
  const int b = bh >> 4, h = bh & 15;

  short8 qf[2][2];
#pragma unroll
  for (int m = 0; m < 2; ++m)
#pragma unroll
    for (int ks = 0; ks < 2; ++ks) {
      size_t grow = (size_t)(b * 1024 + qt * 128 + wid * 32 + m * 16 + lr);
      qf[m][ks] = *(const short8*)(QKV + grow * 3072 + h * 64 + ks * 32 + hi * 8);
    }

  unsigned long long keepm = 0ull;
#pragma unroll
  for (int kt = 0; kt < 16; ++kt)
#pragma unroll
    for (int n = 0; n < 4; ++n)
      if (mask[b * 1024 + kt * 64 + n * 16 + lr] != 0)
        keepm |= (1ull << (kt * 4 + n));

  const u16* Kbase = QKV + (size_t)(b * 1024) * 3072 + 1024 + h * 64;
  const u16* Vbase = Vt + (size_t)(h * 64) * 4096 + b * 1024;
  const int sr = lane >> 3;
  const int sc = lane & 7;

  auto stage = [&](int bf, int kt) {
#pragma unroll
    for (int j = 0; j < 2; ++j) {
      int r = wid * 16 + j * 8 + sr;
      int cs = sc ^ (r & 7);
      gload16(Kbase + (size_t)(kt * 64 + r) * 3072 + cs * 8,
              &kl[bf][(wid * 16 + j * 8) * 64]);
      gload16(Vbase + (size_t)r * 4096 + kt * 64 + cs * 8,
              &vl[bf][(wid * 16 + j * 8) * 64]);
    }
  };

  float m_run[2][4], l_run[2][4];
  f32x4 O[2][4];
  const f32x4 zero = {0.f, 0.f, 0.f, 0.f};
#pragma unroll
  for (int m = 0; m < 2; ++m) {
#pragma unroll
    for (int r = 0; r < 4; ++r) { m_run[m][r] = -3.0e38f; l_run[m][r] = 0.f; }
#pragma unroll
    for (int d = 0; d < 4; ++d) O[m][d] = zero;
  }

  stage(0, 0);
  __syncthreads();
  int cur = 0;
  for (int kt = 0; kt < 16; ++kt) {
    if (kt + 1 < 16) stage(cur ^ 1, kt + 1);

    short8 kf[4][2];
#pragma unroll
    for (int n = 0; n < 4; ++n) {
      int key = n * 16 + lr;
#pragma unroll
      for (int ks = 0; ks < 2; ++ks) {
        int ch = (hi + 4 * ks) ^ (key & 7);
        kf[n][ks] = *(const short8*)(kl[cur] + key * 64 + ch * 8);
      }
    }
    f32x4 s[2][4];
#pragma unroll
    for (int m = 0; m < 2; ++m)
#pragma unroll
      for (int n = 0; n < 4; ++n) s[m][n] = zero;
#pragma unroll
    for (int ks = 0; ks < 2; ++ks)
#pragma unroll
      for (int m = 0; m < 2; ++m)
#pragma unroll
        for (int n = 0; n < 4; ++n)
          s[m][n] = __builtin_amdgcn_mfma_f32_16x16x32_bf16(qf[m][ks], kf[n][ks], s[m][n], 0, 0, 0);

    bool keep[4];
#pragma unroll
    for (int n = 0; n < 4; ++n)
      keep[n] = (keepm >> (kt * 4 + n)) & 1ull;

#pragma unroll
    for (int m = 0; m < 2; ++m) {
#pragma unroll
      for (int r = 0; r < 4; ++r) {
        float sv[4];
#pragma unroll
        for (int n = 0; n < 4; ++n) {
          float x = s[m][n][r];
          sv[n] = keep[n] ? x : -3.0e38f;
        }
        float tm = fmaxf(fmaxf(sv[0], sv[1]), fmaxf(sv[2], sv[3]));
        tm = fmaxf(tm, __shfl_xor(tm, 1));
        tm = fmaxf(tm, __shfl_xor(tm, 2));
        tm = fmaxf(tm, __shfl_xor(tm, 4));
        tm = fmaxf(tm, __shfl_xor(tm, 8));
        float mo = m_run[m][r];
        float mn = fmaxf(mo, tm);
        float alpha = __expf(mo - mn);
        m_run[m][r] = mn;
        int prow = m * 16 + hi * 4 + r;
        float ps = 0.f;
        u16 pb[4];
#pragma unroll
        for (int n = 0; n < 4; ++n) {
          float p = __expf(sv[n] - mn);
          ps += p;
          pb[n] = f2bf(p);
        }
        l_run[m][r] = l_run[m][r] * alpha + ps;
#pragma unroll
        for (int d = 0; d < 4; ++d) O[m][d][r] *= alpha;
#pragma unroll
        for (int n = 0; n < 4; ++n) {
          int col = n * 16 + lr;
          int ch = (col >> 3) ^ (prow & 7);
          pl[wid][prow * 64 + ch * 8 + (col & 7)] = pb[n];
        }
      }
    }

#pragma unroll
    for (int ks = 0; ks < 2; ++ks) {
      short8 pa[2], vf[4];
#pragma unroll
      for (int m = 0; m < 2; ++m) {
        int prow = m * 16 + lr;
        int ch = (hi + 4 * ks) ^ (prow & 7);
        pa[m] = *(const short8*)(pl[wid] + prow * 64 + ch * 8);
      }
#pragma unroll
      for (int d = 0; d < 4; ++d) {
        int vrow = d * 16 + lr;
        int ch = (hi + 4 * ks) ^ (vrow & 7);
        vf[d] = *(const short8*)(vl[cur] + vrow * 64 + ch * 8);
      }
#pragma unroll
      for (int m = 0; m < 2; ++m)
#pragma unroll
        for (int d = 0; d < 4; ++d)
          O[m][d] = __builtin_amdgcn_mfma_f32_16x16x32_bf16(pa[m], vf[d], O[m][d], 0, 0, 0);
    }
    __syncthreads();
    cur ^= 1;
  }

#pragma unroll
  for (int m = 0; m < 2; ++m) {
#pragma unroll
    for (int r = 0; r < 4; ++r) {
      float l = l_run[m][r];
      l += __shfl_xor(l, 1);
      l += __shfl_xor(l, 2);
      l += __shfl_xor(l, 4);
      l += __shfl_xor(l, 8);
      float inv = 1.0f / l;
      size_t row = (size_t)(b * 1024 + qt * 128 + wid * 32 + m * 16 + hi * 4 + r);
#pragma unroll
      for (int d = 0; d < 4; ++d)
        CTX[row * 1024 + h * 64 + d * 16 + lr] = f2bf(O[m][d][r] * inv);
    }
  }
}

// ---------- allennlp LayerNorm of (xa+xb[+xc]) ----------
__global__ __launch_bounds__(256) void ln_kernel(
    const float* __restrict__ xa, const float* __restrict__ xb,
    const float* __restrict__ xc,
    const float* __restrict__ g, const float* __restrict__ beta,
    float* __restrict__ of, u16* __restrict__ ob) {
  int row = blockIdx.x;
  int tid = threadIdx.x;
  const float* pa = xa + (size_t)row * 1024;
  const float* pb = xb + (size_t)row * 1024;
  const float* pc = xc ? xc + (size_t)row * 1024 : nullptr;
  float v[4];
  float s = 0.f, s2 = 0.f;
#pragma unroll
  for (int j = 0; j < 4; ++j) {
    int c = tid + j * 256;
    float x = pa[c] + pb[c];
    if (pc) x += pc[c];
    v[j] = x; s += x; s2 += x * x;
  }
#pragma unroll
  for (int d = 1; d < 64; d <<= 1) {
    s += __shfl_xor(s, d);
    s2 += __shfl_xor(s2, d);
  }
  __shared__ float red[8];
  int w = tid >> 6, lane = tid & 63;
  if (lane == 0) { red[w] = s; red[4 + w] = s2; }
  __syncthreads();
  s = red[0] + red[1] + red[2] + red[3];
  s2 = red[4] + red[5] + red[6] + red[7];
  float mean = s * (1.0f / 1024.0f);
  float var = fmaxf((s2 - 1024.0f * mean * mean) * (1.0f / 1023.0f), 0.0f);
  float rden = 1.0f / (sqrtf(var) + 1e-6f);
#pragma unroll
  for (int j = 0; j < 4; ++j) {
    int c = tid + j * 256;
    float y = g[c] * (v[j] - mean) * rden + beta[c];
    of[(size_t)row * 1024 + c] = y;
    if (ob) ob[(size_t)row * 1024 + c] = f2bf(y);
  }
}

extern "C" void kernel_launch(void* const* d_in, const int* in_sizes, int n_in,
                              void* d_out, int out_size, void* d_ws, size_t ws_size,
                              hipStream_t stream) {
  const float* src   = (const float*)d_in[0];
  const int*   mask  = (const int*)d_in[1];
  const float* q_w   = (const float*)d_in[2];
  const float* q_b   = (const float*)d_in[3];
  const float* kv_w  = (const float*)d_in[4];
  const float* kv_b  = (const float*)d_in[5];
  const float* out_w = (const float*)d_in[6];
  const float* out_b = (const float*)d_in[7];
  const float* w1    = (const float*)d_in[8];
  const float* b1    = (const float*)d_in[9];
  const float* w2    = (const float*)d_in[10];
  const float* b2    = (const float*)d_in[11];
  const float* g1    = (const float*)d_in[12];
  const float* be1   = (const float*)d_in[13];
  const float* g2    = (const float*)d_in[14];
  const float* be2   = (const float*)d_in[15];
  float* out = (float*)d_out;

  char* ws = (char*)d_ws;
  const size_t MB = 1024 * 1024;
  const int BIG = 1 << 30;
  u16*  Xbf   = (u16*)(ws + 0);          //  8MB (4096x1024)
  u16*  CTX   = (u16*)(ws + 8 * MB);     //  8MB
  u16*  WqkvT = (u16*)(ws + 16 * MB);    //  6MB (3072x1024)
  u16*  WoT   = (u16*)(ws + 22 * MB);    //  2MB
  u16*  W1T   = (u16*)(ws + 24 * MB);    //  8MB (4096x1024)
  u16*  W2T   = (u16*)(ws + 32 * MB);    //  8MB (1024x4096)
  u16*  QKV   = (u16*)(ws + 40 * MB);    // 24MB (4096x3072)
  u16*  Vt    = (u16*)(ws + 64 * MB);    //  8MB (1024x4096)
  u16*  F1b   = (u16*)(ws + 40 * MB);    // 32MB (4096x4096), aliases QKV+Vt (dead)
  float* AOUT = (float*)(ws + 72 * MB);  // 16MB
  float* OUT1F= (float*)(ws + 88 * MB);  // 16MB
  u16*  OUT1B = (u16*)(ws + 104 * MB);   //  8MB
  float* F2F  = (float*)(ws + 72 * MB);  // 16MB, aliases AOUT (dead after LN1)

  // 1. prep: cast src + all weight transposes (one dispatch)
  prep_kernel<<<dim3(16384), dim3(256), 0, stream>>>(
      src, q_w, kv_w, out_w, w1, w2, Xbf, WqkvT, WoT, W1T, W2T);
  // 2. QKV = X @ [q_w|kv_w] + [q_b|kv_b]; Q cols scaled 1/8
  gemm_ring_kernel<256, 8, u16, false><<<dim3(12, 16), dim3(512), 0, stream>>>(
      Xbf, 1024, WqkvT, 1024, q_b, kv_b, 1024, QKV, 3072, 1024, 0.125f);
  // 3. Vt[dh][m] = QKV[m][2048+dh]
  transpose_u16_kernel<<<dim3(32, 128), dim3(32, 8), 0, stream>>>(QKV, 3072, 2048, Vt, 4096);
  // 4. fused attention -> CTX
  attn_kernel<<<dim3(64, 8), dim3(256), 0, stream>>>(QKV, Vt, mask, CTX);
  // 5. attn_out = CTX @ out_w + out_b
  gemm_ring_kernel<128, 4, float, false><<<dim3(8, 32), dim3(256), 0, stream>>>(
      CTX, 1024, WoT, 1024, out_b, nullptr, BIG, AOUT, 1024, 1024, 1.0f);
  // 6. out1 = LN(src + attn_out)
  ln_kernel<<<dim3(4096), dim3(256), 0, stream>>>(src, AOUT, nullptr, g1, be1, OUT1F, OUT1B);
  // 7. ffn1 = relu(out1 @ w1 + b1)
  gemm_ring_kernel<256, 8, u16, true><<<dim3(16, 16), dim3(512), 0, stream>>>(
      OUT1B, 1024, W1T, 1024, b1, nullptr, BIG, F1b, 4096, 1024, 1.0f);
  // 8. ffn2 = ffn1 @ w2 + b2  (K=4096, no split-K needed at 2 blocks/CU)
  gemm_ring_kernel<128, 4, float, false><<<dim3(8, 32), dim3(256), 0, stream>>>(
      F1b, 4096, W2T, 4096, b2, nullptr, BIG, F2F, 1024, 4096, 1.0f);
  // 9. out = LN(out1 + ffn2)
  ln_kernel<<<dim3(4096), dim3(256), 0, stream>>>(OUT1F, F2F, nullptr, g2, be2, out, nullptr);
  (void)in_sizes; (void)n_in; (void)out_size; (void)ws_size;
}

// Round 5
// 316.588 us; speedup vs baseline: 1.3242x; 1.0967x over previous
//
#include <hip/hip_runtime.h>

#define DEV __device__ __forceinline__
#define SB0 __builtin_amdgcn_sched_barrier(0)

typedef unsigned short u16;
typedef __attribute__((ext_vector_type(4))) float f32x4;
typedef __attribute__((ext_vector_type(8))) short short8;

DEV u16 f2bf(float f) {
  union { float f; unsigned u; } c; c.f = f;
  unsigned u = c.u;
  unsigned r = (u + 0x7FFFu + ((u >> 16) & 1u)) >> 16;
  return (u16)r;
}
DEV float bf2f(u16 h) {
  union { unsigned u; float f; } c; c.u = ((unsigned)h) << 16;
  return c.f;
}
DEV unsigned cvtpk(float a, float b) {  // D[15:0]=bf16(a), D[31:16]=bf16(b), RNE
  unsigned r;
  asm("v_cvt_pk_bf16_f32 %0, %1, %2" : "=v"(r) : "v"(a), "v"(b));
  return r;
}

DEV void gload16(const void* g, void* l) {
  __builtin_amdgcn_global_load_lds(
      (__attribute__((address_space(1))) void*)(g),
      (__attribute__((address_space(3))) void*)(l), 16, 0, 0);
}
DEV void vmc8() { asm volatile("s_waitcnt vmcnt(8)" ::: "memory"); SB0; }
DEV void vmc0() { asm volatile("s_waitcnt vmcnt(0)" ::: "memory"); SB0; }

// ---------- merged prep: cast src->bf16 + 5 weight transposes ----------
__global__ __launch_bounds__(256) void prep_kernel(
    const float* __restrict__ src, const float* __restrict__ q_w,
    const float* __restrict__ kv_w, const float* __restrict__ out_w,
    const float* __restrict__ w1, const float* __restrict__ w2,
    u16* __restrict__ Xbf, u16* __restrict__ WqkvT, u16* __restrict__ WoT,
    u16* __restrict__ W1T, u16* __restrict__ W2T) {
  __shared__ float tile[32 * 33];
  int bb = blockIdx.x, tid = threadIdx.x;
  if (bb < 4096) {  // cast 4M floats
    int i = bb * 256 + tid;
    float4 v = reinterpret_cast<const float4*>(src)[i];
    ushort4 o;
    o.x = f2bf(v.x); o.y = f2bf(v.y); o.z = f2bf(v.z); o.w = f2bf(v.w);
    reinterpret_cast<ushort4*>(Xbf)[i] = o;
    return;
  }
  const float* in; u16* outp; int ld_in, ld_out, bx, by;
  if (bb < 5120)       { int t = bb - 4096;  in = q_w;   outp = WqkvT; ld_in = 1024; ld_out = 1024; bx = t & 31;  by = t >> 5; }
  else if (bb < 7168)  { int t = bb - 5120;  in = kv_w;  outp = WqkvT + (size_t)1024 * 1024; ld_in = 2048; ld_out = 1024; bx = t & 63;  by = t >> 6; }
  else if (bb < 8192)  { int t = bb - 7168;  in = out_w; outp = WoT;   ld_in = 1024; ld_out = 1024; bx = t & 31;  by = t >> 5; }
  else if (bb < 12288) { int t = bb - 8192;  in = w1;    outp = W1T;   ld_in = 4096; ld_out = 1024; bx = t & 127; by = t >> 7; }
  else                 { int t = bb - 12288; in = w2;    outp = W2T;   ld_in = 1024; ld_out = 4096; bx = t & 31;  by = t >> 5; }
  int tx = tid & 31, ty = tid >> 5;
  int c0 = bx * 32, r0 = by * 32;
#pragma unroll
  for (int j = 0; j < 4; ++j)
    tile[(ty + j * 8) * 33 + tx] = in[(size_t)(r0 + ty + j * 8) * ld_in + c0 + tx];
  __syncthreads();
#pragma unroll
  for (int j = 0; j < 4; ++j)
    outp[(size_t)(c0 + ty + j * 8) * ld_out + r0 + tx] = f2bf(tile[tx * 33 + ty + j * 8]);
}

// ---------- Vtp extraction: Vtp[dh][tok-block*64 + p] = V[tok-block*64+key(p)][dh]
// Per-64 permutation p(k): n=k>>4 (within 64), w=k&15:
//   p = (n>>1)*32 + (w>>2)*8 + (n&1)*4 + (w&3)
// chosen so PV MFMA fragments read contiguous b128 while P stays in registers.
__global__ __launch_bounds__(256) void transpose_vtp_kernel(
    const u16* __restrict__ in, u16* __restrict__ out) {
  __shared__ float tile[32][33];
  int c0 = blockIdx.x * 32, r0 = blockIdx.y * 32;  // c0 = dh, r0 = token
  int tx = threadIdx.x, ty = threadIdx.y;
#pragma unroll
  for (int j = 0; j < 4; ++j)
    tile[ty + j * 8][tx] = bf2f(in[(size_t)(r0 + ty + j * 8) * 3072 + 2048 + c0 + tx]);
  __syncthreads();
  int k = r0 + tx;
  int base = k & ~63, kb = k & 63;
  int n = kb >> 4, w = kb & 15;
  int p = ((n >> 1) << 5) | ((w >> 2) << 3) | ((n & 1) << 2) | (w & 3);
#pragma unroll
  for (int j = 0; j < 4; ++j)
    out[(size_t)(c0 + ty + j * 8) * 4096 + base + p] = f2bf(tile[tx][ty + j * 8]);
}

// ---------- ring-4 pipelined GEMM (unchanged from R3) ----------
template <int BM, int NWARP, typename OutT, bool RELU>
__global__ __launch_bounds__(NWARP * 64, 2) void gemm_ring_kernel(
    const u16* __restrict__ A, int lda,
    const u16* __restrict__ Bt, int ldb,
    const float* __restrict__ bias, const float* __restrict__ bias2, int split,
    OutT* __restrict__ C, int ldc, int K, float scale) {
  constexpr int MT = BM / 32;
  constexpr int PWR = BM / 2;
  constexpr int WN = NWARP / 2;
  constexpr int SLOT = 2 * BM * 32;
  __shared__ __align__(16) u16 ring[4][SLOT];

  const int tid = threadIdx.x;
  const int lane = tid & 63, wid = tid >> 6;
  const int wr = wid / WN, wc = wid % WN;
  const int lr = lane & 15, hi = lane >> 4;

  const int gx = gridDim.x;
  const int nwg = gx * gridDim.y;
  const int orig = blockIdx.y * gx + blockIdx.x;
  const int q = nwg >> 3, r8 = nwg & 7, xcd = orig & 7, oo = orig >> 3;
  const int lid = (xcd < r8 ? xcd * (q + 1) : r8 * (q + 1) + (xcd - r8) * q) + oo;
  const int rb = lid / gx, cb = lid % gx;

  const u16* Abase = A + (size_t)rb * BM * lda;
  const u16* Bbase = Bt + (size_t)cb * BM * ldb;

  auto stage = [&](int slot, int kt) {
#pragma unroll
    for (int j = 0; j < 2; ++j) {
      int ch = wid * 2 + j;
      int row = ch * 16 + (lane >> 2);
      int cs = (lane & 3) ^ ((row >> 1) & 3);
      gload16(Abase + (size_t)row * lda + kt * 32 + cs * 8, &ring[slot][ch * 512]);
      gload16(Bbase + (size_t)row * ldb + kt * 32 + cs * 8, &ring[slot][BM * 32 + ch * 512]);
    }
  };

  f32x4 acc[MT][4];
  const f32x4 zero = {0.f, 0.f, 0.f, 0.f};
#pragma unroll
  for (int m = 0; m < MT; ++m)
#pragma unroll
    for (int n = 0; n < 4; ++n) acc[m][n] = zero;

  const int NT = K >> 5;
  stage(0, 0); stage(1, 1); stage(2, 2);
  vmc8();
  __builtin_amdgcn_s_barrier(); SB0;

  const int sw = (lr >> 1) & 3;
  for (int k = 0; k < NT; ++k) {
    const u16* la = &ring[k & 3][0];
    const u16* lb = &ring[k & 3][BM * 32];
    short8 bf[4], af[MT];
#pragma unroll
    for (int n = 0; n < 4; ++n)
      bf[n] = *(const short8*)(lb + (wc * 64 + n * 16 + lr) * 32 + ((hi ^ sw) * 8));
#pragma unroll
    for (int m = 0; m < MT; ++m)
      af[m] = *(const short8*)(la + (wr * PWR + m * 16 + lr) * 32 + ((hi ^ sw) * 8));
    if (k + 3 < NT) stage((k + 3) & 3, k + 3);
    __builtin_amdgcn_s_setprio(1);
#pragma unroll
    for (int m = 0; m < MT; ++m)
#pragma unroll
      for (int n = 0; n < 4; ++n)
        acc[m][n] = __builtin_amdgcn_mfma_f32_16x16x32_bf16(af[m], bf[n], acc[m][n], 0, 0, 0);
    __builtin_amdgcn_s_setprio(0);
    if (k + 4 < NT) vmc8();
    else if (k + 1 < NT) vmc0();
    __builtin_amdgcn_s_barrier(); SB0;
  }

#pragma unroll
  for (int m = 0; m < MT; ++m) {
    int row0 = rb * BM + wr * PWR + m * 16 + hi * 4;
#pragma unroll
    for (int n = 0; n < 4; ++n) {
      int col = cb * BM + wc * 64 + n * 16 + lr;
      float bv = 0.0f, sc = scale;
      if (col < split) bv = bias[col];
      else { bv = bias2[col - split]; sc = 1.0f; }
#pragma unroll
      for (int r = 0; r < 4; ++r) {
        float v = (acc[m][n][r] + bv) * sc;
        if (RELU) v = fmaxf(v, 0.0f);
        if constexpr (sizeof(OutT) == 2)
          C[(size_t)(row0 + r) * ldc + col] = f2bf(v);
        else
          C[(size_t)(row0 + r) * ldc + col] = v;
      }
    }
  }
}

// ---------- fused flash attention, swapped-QK^T, P fully in registers ----------
// 8 waves x 16 q-rows (512 thr). S = mfma(K,Q): lane owns query lr, keys
// n*16+hi*4+r. PV computed as O^T = mfma(Vtp, P) with the per-64 key
// permutation folded into Vtp's global layout, so P fragments come straight
// from s-registers via v_cvt_pk_bf16_f32 (no LDS round-trip).
__global__ __launch_bounds__(512, 2) void attn_kernel(
    const u16* __restrict__ QKV, const u16* __restrict__ Vtp,
    const int* __restrict__ mask, u16* __restrict__ CTX) {
  __shared__ __align__(16) u16 kl[2][64 * 64];
  __shared__ __align__(16) u16 vl[2][64 * 64];
  __shared__ unsigned long long mask_lds[16];
  const int lane = threadIdx.x & 63;
  const int wid = threadIdx.x >> 6;
  const int lr = lane & 15, hi = lane >> 4;
  const int bh = blockIdx.x, qt = blockIdx.y;
  const int b = bh >> 4, h = bh & 15;

  // Q fragment (B-operand): query = qt*128 + wid*16 + lr
  const size_t qrow = (size_t)(b * 1024 + qt * 128 + wid * 16 + lr);
  short8 qf[2];
#pragma unroll
  for (int ks = 0; ks < 2; ++ks)
    qf[ks] = *(const short8*)(QKV + qrow * 3072 + h * 64 + ks * 32 + hi * 8);

  // per-tile key masks via ballot (2 tiles per wave)
#pragma unroll
  for (int i = 0; i < 2; ++i) {
    int kt = wid * 2 + i;
    unsigned long long bal = __ballot(mask[b * 1024 + kt * 64 + lane] != 0);
    if (lane == 0) mask_lds[kt] = bal;
  }

  const u16* Kbase = QKV + (size_t)(b * 1024) * 3072 + 1024 + h * 64;
  const u16* Vbase = Vtp + (size_t)(h * 64) * 4096 + b * 1024;

  auto stage = [&](int bf, int kt) {
    int r = wid * 8 + (lane >> 3);
    int cs = (lane & 7) ^ (r & 7);
    gload16(Kbase + (size_t)(kt * 64 + r) * 3072 + cs * 8, &kl[bf][wid * 8 * 64]);
    gload16(Vbase + (size_t)r * 4096 + kt * 64 + cs * 8, &vl[bf][wid * 8 * 64]);
  };

  float m_run = -3.0e38f, l_run = 0.0f;
  f32x4 O[4];
  const f32x4 zero = {0.f, 0.f, 0.f, 0.f};
#pragma unroll
  for (int d = 0; d < 4; ++d) O[d] = zero;

  stage(0, 0);
  __syncthreads();
  int cur = 0;
  for (int kt = 0; kt < 16; ++kt) {
    if (kt + 1 < 16) stage(cur ^ 1, kt + 1);

    // S = K . Q^T : s[n][r] = logit(query lr, key n*16+hi*4+r)
    f32x4 s[4];
#pragma unroll
    for (int n = 0; n < 4; ++n) s[n] = zero;
    __builtin_amdgcn_s_setprio(1);
#pragma unroll
    for (int n = 0; n < 4; ++n) {
      int key = n * 16 + lr;
#pragma unroll
      for (int ks = 0; ks < 2; ++ks) {
        int ch = (hi + 4 * ks) ^ (key & 7);
        short8 kf = *(const short8*)(kl[cur] + key * 64 + ch * 8);
        s[n] = __builtin_amdgcn_mfma_f32_16x16x32_bf16(kf, qf[ks], s[n], 0, 0, 0);
      }
    }
    __builtin_amdgcn_s_setprio(0);

    unsigned long long mk = mask_lds[kt];
    if (mk != ~0ull) {
#pragma unroll
      for (int n = 0; n < 4; ++n)
#pragma unroll
        for (int r = 0; r < 4; ++r)
          if (!((mk >> (n * 16 + hi * 4 + r)) & 1ull)) s[n][r] = -3.0e38f;
    }

    // row max: 16 in-lane + 2 shfls (hi groups)
    float tm = -3.0e38f;
#pragma unroll
    for (int n = 0; n < 4; ++n)
      tm = fmaxf(tm, fmaxf(fmaxf(s[n][0], s[n][1]), fmaxf(s[n][2], s[n][3])));
    tm = fmaxf(tm, __shfl_xor(tm, 16));
    tm = fmaxf(tm, __shfl_xor(tm, 32));

    float mo = m_run;
    bool grow = __any(tm > mo);
    float mn = grow ? fmaxf(mo, tm) : mo;
    m_run = mn;
    float ps = 0.0f;
#pragma unroll
    for (int n = 0; n < 4; ++n)
#pragma unroll
      for (int r = 0; r < 4; ++r) {
        float p = __expf(s[n][r] - mn);
        s[n][r] = p;
        ps += p;
      }
    if (grow) {
      float alpha = __expf(mo - mn);
      l_run = l_run * alpha + ps;
#pragma unroll
      for (int d = 0; d < 4; ++d)
#pragma unroll
        for (int r = 0; r < 4; ++r) O[d][r] *= alpha;
    } else {
      l_run += ps;
    }

    // PV: O^T += Vtp-frag . P-frag (P straight from registers)
#pragma unroll
    for (int ks = 0; ks < 2; ++ks) {
      union { unsigned u[4]; short8 s8; } pf;
      pf.u[0] = cvtpk(s[2 * ks][0], s[2 * ks][1]);
      pf.u[1] = cvtpk(s[2 * ks][2], s[2 * ks][3]);
      pf.u[2] = cvtpk(s[2 * ks + 1][0], s[2 * ks + 1][1]);
      pf.u[3] = cvtpk(s[2 * ks + 1][2], s[2 * ks + 1][3]);
      __builtin_amdgcn_s_setprio(1);
#pragma unroll
      for (int d = 0; d < 4; ++d) {
        int vrow = d * 16 + lr;
        int ch = (hi + 4 * ks) ^ (vrow & 7);
        short8 vf = *(const short8*)(vl[cur] + vrow * 64 + ch * 8);
        O[d] = __builtin_amdgcn_mfma_f32_16x16x32_bf16(vf, pf.s8, O[d], 0, 0, 0);
      }
      __builtin_amdgcn_s_setprio(0);
    }
    __syncthreads();
    cur ^= 1;
  }

  float l = l_run;
  l += __shfl_xor(l, 16);
  l += __shfl_xor(l, 32);
  float inv = 1.0f / l;
#pragma unroll
  for (int dt = 0; dt < 4; ++dt) {
    uint2 w;
    w.x = cvtpk(O[dt][0] * inv, O[dt][1] * inv);
    w.y = cvtpk(O[dt][2] * inv, O[dt][3] * inv);
    *(uint2*)(CTX + qrow * 1024 + h * 64 + dt * 16 + hi * 4) = w;
  }
}

// ---------- allennlp LayerNorm of (xa+xb[+xc]) ----------
__global__ __launch_bounds__(256) void ln_kernel(
    const float* __restrict__ xa, const float* __restrict__ xb,
    const float* __restrict__ xc,
    const float* __restrict__ g, const float* __restrict__ beta,
    float* __restrict__ of, u16* __restrict__ ob) {
  int row = blockIdx.x;
  int tid = threadIdx.x;
  const float* pa = xa + (size_t)row * 1024;
  const float* pb = xb + (size_t)row * 1024;
  const float* pc = xc ? xc + (size_t)row * 1024 : nullptr;
  float v[4];
  float s = 0.f, s2 = 0.f;
#pragma unroll
  for (int j = 0; j < 4; ++j) {
    int c = tid + j * 256;
    float x = pa[c] + pb[c];
    if (pc) x += pc[c];
    v[j] = x; s += x; s2 += x * x;
  }
#pragma unroll
  for (int d = 1; d < 64; d <<= 1) {
    s += __shfl_xor(s, d);
    s2 += __shfl_xor(s2, d);
  }
  __shared__ float red[8];
  int w = tid >> 6, lane = tid & 63;
  if (lane == 0) { red[w] = s; red[4 + w] = s2; }
  __syncthreads();
  s = red[0] + red[1] + red[2] + red[3];
  s2 = red[4] + red[5] + red[6] + red[7];
  float mean = s * (1.0f / 1024.0f);
  float var = fmaxf((s2 - 1024.0f * mean * mean) * (1.0f / 1023.0f), 0.0f);
  float rden = 1.0f / (sqrtf(var) + 1e-6f);
#pragma unroll
  for (int j = 0; j < 4; ++j) {
    int c = tid + j * 256;
    float y = g[c] * (v[j] - mean) * rden + beta[c];
    of[(size_t)row * 1024 + c] = y;
    if (ob) ob[(size_t)row * 1024 + c] = f2bf(y);
  }
}

extern "C" void kernel_launch(void* const* d_in, const int* in_sizes, int n_in,
                              void* d_out, int out_size, void* d_ws, size_t ws_size,
                              hipStream_t stream) {
  const float* src   = (const float*)d_in[0];
  const int*   mask  = (const int*)d_in[1];
  const float* q_w   = (const float*)d_in[2];
  const float* q_b   = (const float*)d_in[3];
  const float* kv_w  = (const float*)d_in[4];
  const float* kv_b  = (const float*)d_in[5];
  const float* out_w = (const float*)d_in[6];
  const float* out_b = (const float*)d_in[7];
  const float* w1    = (const float*)d_in[8];
  const float* b1    = (const float*)d_in[9];
  const float* w2    = (const float*)d_in[10];
  const float* b2    = (const float*)d_in[11];
  const float* g1    = (const float*)d_in[12];
  const float* be1   = (const float*)d_in[13];
  const float* g2    = (const float*)d_in[14];
  const float* be2   = (const float*)d_in[15];
  float* out = (float*)d_out;

  char* ws = (char*)d_ws;
  const size_t MB = 1024 * 1024;
  const int BIG = 1 << 30;
  u16*  Xbf   = (u16*)(ws + 0);          //  8MB (4096x1024)
  u16*  CTX   = (u16*)(ws + 8 * MB);     //  8MB
  u16*  WqkvT = (u16*)(ws + 16 * MB);    //  6MB (3072x1024)
  u16*  WoT   = (u16*)(ws + 22 * MB);    //  2MB
  u16*  W1T   = (u16*)(ws + 24 * MB);    //  8MB (4096x1024)
  u16*  W2T   = (u16*)(ws + 32 * MB);    //  8MB (1024x4096)
  u16*  QKV   = (u16*)(ws + 40 * MB);    // 24MB (4096x3072)
  u16*  Vtp   = (u16*)(ws + 64 * MB);    //  8MB (1024x4096), key-permuted
  u16*  F1b   = (u16*)(ws + 40 * MB);    // 32MB (4096x4096), aliases QKV+Vtp (dead)
  float* AOUT = (float*)(ws + 72 * MB);  // 16MB
  float* OUT1F= (float*)(ws + 88 * MB);  // 16MB
  u16*  OUT1B = (u16*)(ws + 104 * MB);   //  8MB
  float* F2F  = (float*)(ws + 72 * MB);  // 16MB, aliases AOUT (dead after LN1)

  // 1. prep: cast src + all weight transposes (one dispatch)
  prep_kernel<<<dim3(16384), dim3(256), 0, stream>>>(
      src, q_w, kv_w, out_w, w1, w2, Xbf, WqkvT, WoT, W1T, W2T);
  // 2. QKV = X @ [q_w|kv_w] + [q_b|kv_b]; Q cols scaled 1/8
  gemm_ring_kernel<256, 8, u16, false><<<dim3(12, 16), dim3(512), 0, stream>>>(
      Xbf, 1024, WqkvT, 1024, q_b, kv_b, 1024, QKV, 3072, 1024, 0.125f);
  // 3. Vtp[dh][tok] = V (key-permuted per 64-block)
  transpose_vtp_kernel<<<dim3(32, 128), dim3(32, 8), 0, stream>>>(QKV, Vtp);
  // 4. fused attention -> CTX
  attn_kernel<<<dim3(64, 8), dim3(512), 0, stream>>>(QKV, Vtp, mask, CTX);
  // 5. attn_out = CTX @ out_w + out_b
  gemm_ring_kernel<128, 4, float, false><<<dim3(8, 32), dim3(256), 0, stream>>>(
      CTX, 1024, WoT, 1024, out_b, nullptr, BIG, AOUT, 1024, 1024, 1.0f);
  // 6. out1 = LN(src + attn_out)
  ln_kernel<<<dim3(4096), dim3(256), 0, stream>>>(src, AOUT, nullptr, g1, be1, OUT1F, OUT1B);
  // 7. ffn1 = relu(out1 @ w1 + b1)
  gemm_ring_kernel<256, 8, u16, true><<<dim3(16, 16), dim3(512), 0, stream>>>(
      OUT1B, 1024, W1T, 1024, b1, nullptr, BIG, F1b, 4096, 1024, 1.0f);
  // 8. ffn2 = ffn1 @ w2 + b2
  gemm_ring_kernel<128, 4, float, false><<<dim3(8, 32), dim3(256), 0, stream>>>(
      F1b, 4096, W2T, 4096, b2, nullptr, BIG, F2F, 1024, 4096, 1.0f);
  // 9. out = LN(out1 + ffn2)
  ln_kernel<<<dim3(4096), dim3(256), 0, stream>>>(OUT1F, F2F, nullptr, g2, be2, out, nullptr);
  (void)in_sizes; (void)n_in; (void)out_size; (void)ws_size;
}